// Round 5
// baseline (59778.772 us; speedup 1.0000x reference)
//
#include <hip/hip_runtime.h>
#include <stdint.h>

#define TT 128
#define BB 64
#define DD 1024
#define G3 3072
#define NGB 168          // phase-1 GEMM blocks (2 jobs each = 336 jobs)
#define NBLK 232         // + 64 attention blocks

typedef unsigned short u16;
typedef unsigned int u32;
typedef __attribute__((ext_vector_type(8))) short bf16x8;
typedef __attribute__((ext_vector_type(4))) short s16x4;
typedef __attribute__((ext_vector_type(4))) float f32x4;

__device__ __forceinline__ float b2f(u16 h){ u32 u = ((u32)h)<<16; float f; __builtin_memcpy(&f,&u,4); return f; }
__device__ __forceinline__ u16 f2b(float f){ u32 u; __builtin_memcpy(&u,&f,4); u = (u + 0x7fffu + ((u>>16)&1u))>>16; return (u16)u; }
__device__ __forceinline__ float sigm(float x){ return 1.f/(1.f+__expf(-x)); }
__device__ __forceinline__ float tanh_(float x){
  if (x > 10.f) return 1.f;
  if (x < -10.f) return -1.f;
  float e = __expf(2.f*x); return (e-1.f)/(e+1.f);
}

struct DPar {
  const u16 *A1,*A2,*A3,*A4,*A5,*A6;   // bf16 weights
  const float* feat;                    // fp32 features, converted on the fly
  u16 *ghist,*cb,*qselb,*qnewb,*eb;
  float *scores,*parties,*gf,*ef;
  float *GIGa,*GIGb,*GHG,*GHP,*GIE,*GIPa,*GIPb,*GHE;
  const float *bihg,*bhhg,*bihp,*bhhp,*bihe,*bhhe,*watt;
  const int* spk;
  float* out;
  u32* slots;
};

// ---- grid barrier: per-block release slot store + per-thread acquire poll ----
// __syncthreads drains each wave's vmcnt (compiler semantics), release flushes
// L2 to the agent coherence point, acquire invalidates stale lines. No RMW.
__device__ void gbar(u32* slots, int blk, u32 ep) {
  __syncthreads();
  if (threadIdx.x == 0)
    __hip_atomic_store(slots + blk, ep, __ATOMIC_RELEASE, __HIP_MEMORY_SCOPE_AGENT);
  if (threadIdx.x < NBLK) {
    while (__hip_atomic_load(slots + threadIdx.x, __ATOMIC_ACQUIRE, __HIP_MEMORY_SCOPE_AGENT) < ep)
      __builtin_amdgcn_s_sleep(2);
  }
  __syncthreads();
}

// ---- A-fragment loaders (bf16 direct; fp32 converted in-flight) ----
__device__ __forceinline__ void loadA(bf16x8& d, const u16* p){ d = *(const bf16x8*)p; }
__device__ __forceinline__ void loadA(bf16x8& d, const float* p){
  f32x4 lo = *(const f32x4*)p;
  f32x4 hi = *(const f32x4*)(p + 4);
  #pragma unroll
  for (int i = 0; i < 4; ++i) { d[i] = (short)f2b(lo[i]); d[i+4] = (short)f2b(hi[i]); }
}

// ---- fragment-direct 64x64-tile GEMM, K=1024 ----
// wave wv: kh=wv>>1 owns K-half (512), nh=wv&1 owns N-half (32 cols).
// Lane layout (round-2 HW-verified): A row = l&15, k = kh*512 + kt*32 + (l>>4)*8;
// W row = n0+nh*32+nt*16+(l&15), same k. k0 applies to W ONLY (concat split).
// C row = bt*16+(l>>4)*4+q, col = nh*32+nt*16+(l&15).
template<typename TA>
__device__ __attribute__((noinline)) void gemm_frag(
    const TA* __restrict__ A, const u16* __restrict__ W, int ldW,
    int k0, int n0, float* __restrict__ C, float* red) {
  const int tid = threadIdx.x;
  const int wv  = tid >> 6;
  const int kh  = wv >> 1;
  const int nh  = wv & 1;
  const int lane = tid & 63;
  const int l15 = lane & 15;
  const int l4  = lane >> 4;
  const TA*  Ab = A + (size_t)l15 * DD + kh * 512 + l4 * 8;
  const u16* Wb = W + (size_t)(n0 + nh*32 + l15) * ldW + k0 + kh * 512 + l4 * 8;

  f32x4 acc[4][2];
  #pragma unroll
  for (int i = 0; i < 4; ++i) { acc[i][0] = (f32x4){0,0,0,0}; acc[i][1] = (f32x4){0,0,0,0}; }

  bf16x8 af[2][4], wf[2][2];
  #pragma unroll
  for (int bt = 0; bt < 4; ++bt) loadA(af[0][bt], Ab + (size_t)bt*16*DD);
  #pragma unroll
  for (int nt = 0; nt < 2; ++nt) wf[0][nt] = *(const bf16x8*)(Wb + (size_t)nt*16*ldW);

  #pragma unroll
  for (int kt = 0; kt < 16; ++kt) {
    const int cur = kt & 1, nxt = cur ^ 1;
    if (kt < 15) {
      const int ko = (kt + 1) * 32;
      #pragma unroll
      for (int bt = 0; bt < 4; ++bt) loadA(af[nxt][bt], Ab + (size_t)bt*16*DD + ko);
      #pragma unroll
      for (int nt = 0; nt < 2; ++nt) wf[nxt][nt] = *(const bf16x8*)(Wb + (size_t)nt*16*ldW + ko);
    }
    #pragma unroll
    for (int bt = 0; bt < 4; ++bt)
      #pragma unroll
      for (int nt = 0; nt < 2; ++nt)
        acc[bt][nt] = __builtin_amdgcn_mfma_f32_16x16x32_bf16(af[cur][bt], wf[cur][nt], acc[bt][nt], 0,0,0);
  }
  // K-half reduction: waves kh=1 park partials in LDS (16KB), kh=0 add + store.
  if (kh == 1) {
    #pragma unroll
    for (int bt = 0; bt < 4; ++bt)
      #pragma unroll
      for (int nt = 0; nt < 2; ++nt)
        #pragma unroll
        for (int q = 0; q < 4; ++q)
          red[(bt*16 + l4*4 + q)*64 + nh*32 + nt*16 + l15] = acc[bt][nt][q];
  }
  __syncthreads();
  if (kh == 0) {
    #pragma unroll
    for (int bt = 0; bt < 4; ++bt)
      #pragma unroll
      for (int nt = 0; nt < 2; ++nt)
        #pragma unroll
        for (int q = 0; q < 4; ++q) {
          const int row = bt*16 + l4*4 + q;
          const int col = nh*32 + nt*16 + l15;
          C[(size_t)row*G3 + n0 + col] = acc[bt][nt][q] + red[row*64 + col];
        }
  }
  __syncthreads();   // red reusable by the next job
}

// ---- combine global GRU (16 blocks x 256 thr): g_t, ghist row t, score_t ----
__device__ void combineG(const DPar& p, int t, int rel) {
  const int gt = rel*256 + (int)threadIdx.x;
  const int b  = gt >> 6;
  const int j0 = (gt & 63) << 4;
  const size_t ob = (size_t)b * G3;
  float gn[16];
  float sc = 0.f;
  #pragma unroll
  for (int gq = 0; gq < 4; ++gq) {
    const int j = j0 + gq*4;
    f32x4 ar = *(const f32x4*)(p.GIGa + ob + j);
    f32x4 az = *(const f32x4*)(p.GIGa + ob + 1024 + j);
    f32x4 an = *(const f32x4*)(p.GIGa + ob + 2048 + j);
    f32x4 br = {0,0,0,0}, bz = {0,0,0,0}, bn = {0,0,0,0};
    f32x4 hr = {0,0,0,0}, hz = {0,0,0,0}, hn = {0,0,0,0};
    if (t) {
      br = *(const f32x4*)(p.GIGb + ob + j);
      bz = *(const f32x4*)(p.GIGb + ob + 1024 + j);
      bn = *(const f32x4*)(p.GIGb + ob + 2048 + j);
      hr = *(const f32x4*)(p.GHG + ob + j);
      hz = *(const f32x4*)(p.GHG + ob + 1024 + j);
      hn = *(const f32x4*)(p.GHG + ob + 2048 + j);
    }
    #pragma unroll
    for (int q = 0; q < 4; ++q) {
      const int jj = j + q;
      float r_ = sigm(ar[q] + br[q] + p.bihg[jj]      + hr[q] + p.bhhg[jj]);
      float z_ = sigm(az[q] + bz[q] + p.bihg[1024+jj] + hz[q] + p.bhhg[1024+jj]);
      float n_ = tanh_(an[q] + bn[q] + p.bihg[2048+jj] + r_*(hn[q] + p.bhhg[2048+jj]));
      float gp = p.gf[(size_t)b*DD + jj];
      float gv = (1.f - z_)*n_ + z_*gp;
      p.gf[(size_t)b*DD + jj] = gv;
      gn[gq*4+q] = gv;
      sc += gv * p.watt[jj];
    }
  }
  bf16x8 h0, h1;
  #pragma unroll
  for (int q = 0; q < 8; ++q) { h0[q] = (short)f2b(gn[q]); h1[q] = (short)f2b(gn[8+q]); }
  u16* gr = p.ghist + (size_t)t*BB*DD + (size_t)b*DD + j0;
  *(bf16x8*)gr = h0; *(bf16x8*)(gr + 8) = h1;
  #pragma unroll
  for (int o = 1; o < 64; o <<= 1) sc += __shfl_xor(sc, o);
  if ((threadIdx.x & 63) == 0) p.scores[t*BB + b] = sc;
}

// ---- combine emotion GRU (16 blocks): e_td, out row td ----
__device__ void combineE(const DPar& p, int td, int rel) {
  const int gt = rel*256 + (int)threadIdx.x;
  const int b  = gt >> 6;
  const int j0 = (gt & 63) << 4;
  const size_t ob = (size_t)b * G3;
  float en[16];
  #pragma unroll
  for (int gq = 0; gq < 4; ++gq) {
    const int j = j0 + gq*4;
    f32x4 ir4 = *(const f32x4*)(p.GIE + ob + j);
    f32x4 iz4 = *(const f32x4*)(p.GIE + ob + 1024 + j);
    f32x4 in4 = *(const f32x4*)(p.GIE + ob + 2048 + j);
    f32x4 hr = {0,0,0,0}, hz = {0,0,0,0}, hn = {0,0,0,0};
    if (td > 0) {
      hr = *(const f32x4*)(p.GHE + ob + j);
      hz = *(const f32x4*)(p.GHE + ob + 1024 + j);
      hn = *(const f32x4*)(p.GHE + ob + 2048 + j);
    }
    #pragma unroll
    for (int q = 0; q < 4; ++q) {
      const int jj = j + q;
      float r_ = sigm(ir4[q] + p.bihe[jj]      + hr[q] + p.bhhe[jj]);
      float z_ = sigm(iz4[q] + p.bihe[1024+jj] + hz[q] + p.bhhe[1024+jj]);
      float n_ = tanh_(in4[q] + p.bihe[2048+jj] + r_*(hn[q] + p.bhhe[2048+jj]));
      float ep = p.ef[(size_t)b*DD + jj];
      float ev = (1.f - z_)*n_ + z_*ep;
      p.ef[(size_t)b*DD + jj] = ev;
      en[gq*4+q] = ev;
    }
  }
  float* orow = p.out + (size_t)td*BB*DD + (size_t)b*DD + j0;
  #pragma unroll
  for (int gq = 0; gq < 4; ++gq) {
    f32x4 v = { en[gq*4], en[gq*4+1], en[gq*4+2], en[gq*4+3] };
    *(f32x4*)(orow + gq*4) = v;
  }
  bf16x8 e0, e1;
  #pragma unroll
  for (int q = 0; q < 8; ++q) { e0[q] = (short)f2b(en[q]); e1[q] = (short)f2b(en[8+q]); }
  u16* er = p.eb + (size_t)b*DD + j0;
  *(bf16x8*)er = e0; *(bf16x8*)(er + 8) = e1;
}

// ---- combine party GRU (16 blocks): speaker slot update; emit qnew_t, qsel_{t+1} ----
__device__ void combineQ(const DPar& p, int t, int rel) {
  const int gt = rel*256 + (int)threadIdx.x;
  const int b  = gt >> 6;
  const int j0 = (gt & 63) << 4;
  const size_t ob = (size_t)b * G3;
  const int spkc = p.spk[t*BB + b];
  const int spkn = (t+1 < TT) ? p.spk[(t+1)*BB + b] : spkc;
  float* prow = p.parties + (size_t)(b*2 + spkc)*DD;
  const float* orow = p.parties + (size_t)(b*2 + spkn)*DD;
  float qn16[16];
  #pragma unroll
  for (int gq = 0; gq < 4; ++gq) {
    const int j = j0 + gq*4;
    f32x4 ar = *(const f32x4*)(p.GIPa + ob + j);
    f32x4 az = *(const f32x4*)(p.GIPa + ob + 1024 + j);
    f32x4 an = *(const f32x4*)(p.GIPa + ob + 2048 + j);
    f32x4 br = {0,0,0,0}, bz = {0,0,0,0}, bn = {0,0,0,0};
    f32x4 hr = {0,0,0,0}, hz = {0,0,0,0}, hn = {0,0,0,0};
    if (t) {
      br = *(const f32x4*)(p.GIPb + ob + j);
      bz = *(const f32x4*)(p.GIPb + ob + 1024 + j);
      bn = *(const f32x4*)(p.GIPb + ob + 2048 + j);
      hr = *(const f32x4*)(p.GHP + ob + j);
      hz = *(const f32x4*)(p.GHP + ob + 1024 + j);
      hn = *(const f32x4*)(p.GHP + ob + 2048 + j);
    }
    #pragma unroll
    for (int q = 0; q < 4; ++q) {
      const int jj = j + q;
      float r_ = sigm(ar[q] + br[q] + p.bihp[jj]      + hr[q] + p.bhhp[jj]);
      float z_ = sigm(az[q] + bz[q] + p.bihp[1024+jj] + hz[q] + p.bhhp[1024+jj]);
      float n_ = tanh_(an[q] + bn[q] + p.bihp[2048+jj] + r_*(hn[q] + p.bhhp[2048+jj]));
      float h  = prow[jj];
      float qv = (1.f - z_)*n_ + z_*h;
      prow[jj] = qv;
      qn16[gq*4+q] = qv;
    }
  }
  bf16x8 qn0, qn1, qs0, qs1;
  #pragma unroll
  for (int q = 0; q < 8; ++q) {
    qn0[q] = (short)f2b(qn16[q]);
    qn1[q] = (short)f2b(qn16[8+q]);
    qs0[q] = (spkn == spkc) ? qn0[q] : (short)f2b(orow[j0+q]);
    qs1[q] = (spkn == spkc) ? qn1[q] : (short)f2b(orow[j0+8+q]);
  }
  u16* qnp = p.qnewb + (size_t)b*DD + j0;
  u16* qsp = p.qselb + (size_t)b*DD + j0;
  *(bf16x8*)qnp = qn0; *(bf16x8*)(qnp+8) = qn1;
  *(bf16x8*)qsp = qs0; *(bf16x8*)(qsp+8) = qs1;
}

// ---- attention (64 blocks, one per batch): c_t = softmax(scores[<t]) . ghist[<t] ----
__device__ void attn_run(const DPar& p, int t, int b, float* smem) {
  float* al = smem;          // [128] alpha
  float* rs = smem + 128;    // wave partials
  float* part = smem + 160;  // [4][64][16]
  const int tid = threadIdx.x;
  float s = (tid < t) ? p.scores[tid*BB + b] : -1e30f;
  if (tid < 128) {
    float m = s;
    #pragma unroll
    for (int o = 1; o < 64; o <<= 1) m = fmaxf(m, __shfl_xor(m, o));
    if ((tid & 63) == 0) rs[tid >> 6] = m;
  }
  __syncthreads();
  const float m = fmaxf(rs[0], rs[1]);
  float e = (tid < t) ? __expf(s - m) : 0.f;
  if (tid < 128) {
    float sum = e;
    #pragma unroll
    for (int o = 1; o < 64; o <<= 1) sum += __shfl_xor(sum, o);
    if ((tid & 63) == 0) rs[2 + (tid >> 6)] = sum;
  }
  __syncthreads();
  if (tid < 128) al[tid] = e / (rs[2] + rs[3]);
  __syncthreads();
  const int ug = tid >> 6, dg = tid & 63;
  float acc[16];
  #pragma unroll
  for (int i = 0; i < 16; ++i) acc[i] = 0.f;
  const u16* gb = p.ghist + (size_t)b*DD + dg*16;
  for (int u = ug; u < t; u += 4) {
    const float a = al[u];
    bf16x8 g0 = *(const bf16x8*)(gb + (size_t)u*BB*DD);
    bf16x8 g1 = *(const bf16x8*)(gb + (size_t)u*BB*DD + 8);
    #pragma unroll
    for (int d = 0; d < 8; ++d) { acc[d] += a * b2f((u16)g0[d]); acc[8+d] += a * b2f((u16)g1[d]); }
  }
  #pragma unroll
  for (int i = 0; i < 4; ++i)
    *(f32x4*)(part + ((size_t)ug*64 + dg)*16 + i*4) = (f32x4){acc[i*4],acc[i*4+1],acc[i*4+2],acc[i*4+3]};
  __syncthreads();
  const int d = tid * 4;
  const int dgf = d >> 4, di = d & 15;
  f32x4 sum = {0,0,0,0};
  #pragma unroll
  for (int u2 = 0; u2 < 4; ++u2) sum += *(f32x4*)(part + ((size_t)u2*64 + dgf)*16 + di);
  s16x4 o;
  #pragma unroll
  for (int q = 0; q < 4; ++q) o[q] = (short)f2b(sum[q]);
  *(s16x4*)(p.cb + (size_t)b*DD + d) = o;
  __syncthreads();
}

// ---- phase-1 job dispatch: 7 groups x 48 tiles ----
__device__ void run_job(const DPar& p, int t, int jid, float* red) {
  const int g  = jid / 48;
  const int n0 = (jid % 48) * 64;
  switch (g) {
    case 0:            gemm_frag(p.feat + (size_t)t*BB*DD, p.A1, 2048, 0,    n0, p.GIGa, red); break;
    case 1: if (t)     gemm_frag(p.qselb, p.A1, 2048, 1024, n0, p.GIGb, red); break;
    case 2: if (t)     gemm_frag(p.ghist + (size_t)(t-1)*BB*DD, p.A2, 1024, 0, n0, p.GHG, red); break;
    case 3:            gemm_frag(p.feat + (size_t)t*BB*DD, p.A3, 2048, 0,    n0, p.GIPa, red); break;
    case 4: if (t)     gemm_frag(p.qselb, p.A4, 1024, 0,    n0, p.GHP, red); break;
    case 5: if (t)     gemm_frag(p.qnewb, p.A5, 1024, 0,    n0, p.GIE, red); break;   // emotion step t-1
    case 6: if (t > 1) gemm_frag(p.eb,    p.A6, 1024, 0,    n0, p.GHE, red); break;   // e_{t-2}
  }
}

// ---- persistent kernel (plain launch; 232 blocks <= 256 CUs => co-resident) ----
__global__ void __launch_bounds__(256, 1) drnn_persist(DPar p) {
  __shared__ float smem[8192];   // 32KB: gemm reduce (16KB) / attn scratch (17KB)
  const int blk = blockIdx.x;
  u32 ep = 0;
  for (int t = 0; t < TT; ++t) {
    // phase 1: 336 GEMM jobs + attention c_t
    if (blk < NGB) { run_job(p, t, blk, smem); run_job(p, t, NGB + blk, smem); }
    else if (t)    attn_run(p, t, blk - NGB, smem);
    gbar(p.slots, blk, ++ep);
    // phase 2: GIPb(c_t) + combineG(t) + combineE(t-1)
    if (blk < 48)      { if (t) gemm_frag(p.cb, p.A3, 2048, 1024, blk*64, p.GIPb, smem); }
    else if (blk < 64) combineG(p, t, blk - 48);
    else if (blk < 80) { if (t) combineE(p, t - 1, blk - 64); }
    gbar(p.slots, blk, ++ep);
    // phase 3: combineQ(t)
    if (blk < 16) combineQ(p, t, blk);
    gbar(p.slots, blk, ++ep);
  }
  // epilogue: emotion GRU for step 127
  if (blk < 48)       gemm_frag(p.qnewb, p.A5, 1024, 0, blk*64,      p.GIE, smem);
  else if (blk < 96)  gemm_frag(p.eb,    p.A6, 1024, 0, (blk-48)*64, p.GHE, smem);
  gbar(p.slots, blk, ++ep);
  if (blk < 16) combineE(p, TT-1, blk);
}

// ---- weight fp32 -> bf16 cast ----
__global__ void convertK(const float* __restrict__ Wg, const float* __restrict__ Whg,
                         const float* __restrict__ Wp, const float* __restrict__ Whp,
                         const float* __restrict__ We, const float* __restrict__ Whe,
                         u16* A1, u16* A2, u16* A3, u16* A4, u16* A5, u16* A6) {
  const long n1 = (long)G3*2048/4, n2 = (long)G3*1024/4;
  const long tot = 2*n1 + 4*n2;
  long gid = (long)blockIdx.x*256 + threadIdx.x;
  const long stride = (long)gridDim.x*256;
  for (long i = gid; i < tot; i += stride) {
    const float* src; u16* dst; long o = i;
    if (o < n1) { src = Wg;  dst = A1; }
    else { o -= n1;
      if (o < n2) { src = Whg; dst = A2; }
      else { o -= n2;
        if (o < n1) { src = Wp; dst = A3; }
        else { o -= n1;
          if (o < n2) { src = Whp; dst = A4; }
          else { o -= n2;
            if (o < n2) { src = We; dst = A5; }
            else { o -= n2; src = Whe; dst = A6; }
          }
        }
      }
    }
    f32x4 v = *(const f32x4*)(src + o*4);
    s16x4 w;
    w[0] = (short)f2b(v[0]); w[1] = (short)f2b(v[1]);
    w[2] = (short)f2b(v[2]); w[3] = (short)f2b(v[3]);
    *(s16x4*)(dst + o*4) = w;
  }
}

// ---- zero state + speaker idx (runs every launch; replay/poison-safe) ----
__global__ void initK(float* parties, float* gf, float* ef,
                      u16* cb, u16* qselb, u16* qnewb, u16* eb,
                      const float* spkOH, int* spk, u32* slots) {
  const int i = blockIdx.x*256 + threadIdx.x;
  if (i < BB*2*DD) parties[i] = 0.f;
  if (i < BB*DD) { gf[i] = 0.f; ef[i] = 0.f; cb[i] = 0; qselb[i] = 0; qnewb[i] = 0; eb[i] = 0; }
  if (i < TT*BB) spk[i] = (spkOH[(size_t)i*2 + 1] > 0.5f) ? 1 : 0;
  if (i < NBLK) slots[i] = 0u;
}

extern "C" void kernel_launch(void* const* d_in, const int* in_sizes, int n_in,
                              void* d_out, int out_size, void* d_ws, size_t ws_size,
                              hipStream_t stream) {
  const float* feat  = (const float*)d_in[0];
  const float* spkOH = (const float*)d_in[1];
  const float* Wih_g = (const float*)d_in[2];
  const float* Whh_g = (const float*)d_in[3];
  const float* bih_g = (const float*)d_in[4];
  const float* bhh_g = (const float*)d_in[5];
  const float* Wih_p = (const float*)d_in[6];
  const float* Whh_p = (const float*)d_in[7];
  const float* bih_p = (const float*)d_in[8];
  const float* bhh_p = (const float*)d_in[9];
  const float* Wih_e = (const float*)d_in[10];
  const float* Whh_e = (const float*)d_in[11];
  const float* bih_e = (const float*)d_in[12];
  const float* bhh_e = (const float*)d_in[13];
  const float* watt  = (const float*)d_in[14];

  char* w = (char*)d_ws;
  auto alloc = [&](size_t bytes) -> char* {
    char* r = w; w += (bytes + 255) & ~(size_t)255; return r;
  };
  u16* ghist = (u16*)alloc((size_t)TT*BB*DD*2);
  float* scores = (float*)alloc((size_t)TT*BB*4);
  u16* cb    = (u16*)alloc((size_t)BB*DD*2);
  u16* qselb = (u16*)alloc((size_t)BB*DD*2);
  u16* qnewb = (u16*)alloc((size_t)BB*DD*2);
  u16* eb    = (u16*)alloc((size_t)BB*DD*2);
  float* parties = (float*)alloc((size_t)BB*2*DD*4);
  float* gf  = (float*)alloc((size_t)BB*DD*4);
  float* ef  = (float*)alloc((size_t)BB*DD*4);
  float* GIGa = (float*)alloc((size_t)BB*G3*4);
  float* GIGb = (float*)alloc((size_t)BB*G3*4);
  float* GHG  = (float*)alloc((size_t)BB*G3*4);
  float* GHP  = (float*)alloc((size_t)BB*G3*4);
  float* GIE  = (float*)alloc((size_t)BB*G3*4);
  float* GIPa = (float*)alloc((size_t)BB*G3*4);
  float* GIPb = (float*)alloc((size_t)BB*G3*4);
  float* GHE  = (float*)alloc((size_t)BB*G3*4);
  int* spk    = (int*)alloc((size_t)TT*BB*4);
  u32* slots  = (u32*)alloc(NBLK*4);
  u16* A1 = (u16*)alloc((size_t)G3*2048*2);
  u16* A2 = (u16*)alloc((size_t)G3*1024*2);
  u16* A3 = (u16*)alloc((size_t)G3*2048*2);
  u16* A4 = (u16*)alloc((size_t)G3*1024*2);
  u16* A5 = (u16*)alloc((size_t)G3*1024*2);
  u16* A6 = (u16*)alloc((size_t)G3*1024*2);
  const size_t need = (size_t)(w - (char*)d_ws);   // ~75.0 MB, proven to fit (round 2)
  if (ws_size < need) return;   // fail validation visibly rather than fault

  hipLaunchKernelGGL(convertK, dim3(2048), dim3(256), 0, stream,
                     Wih_g, Whh_g, Wih_p, Whh_p, Wih_e, Whh_e,
                     A1, A2, A3, A4, A5, A6);
  hipLaunchKernelGGL(initK, dim3(512), dim3(256), 0, stream,
                     parties, gf, ef, cb, qselb, qnewb, eb, spkOH, spk, slots);

  DPar p;
  p.A1 = A1; p.A2 = A2; p.A3 = A3; p.A4 = A4; p.A5 = A5; p.A6 = A6;
  p.feat = feat;
  p.ghist = ghist; p.cb = cb; p.qselb = qselb; p.qnewb = qnewb; p.eb = eb;
  p.scores = scores; p.parties = parties; p.gf = gf; p.ef = ef;
  p.GIGa = GIGa; p.GIGb = GIGb; p.GHG = GHG; p.GHP = GHP; p.GIE = GIE;
  p.GIPa = GIPa; p.GIPb = GIPb; p.GHE = GHE;
  p.bihg = bih_g; p.bhhg = bhh_g; p.bihp = bih_p; p.bhhp = bhh_p;
  p.bihe = bih_e; p.bhhe = bhh_e; p.watt = watt;
  p.spk = spk; p.out = (float*)d_out; p.slots = slots;

  hipLaunchKernelGGL(drnn_persist, dim3(NBLK), dim3(256), 0, stream, p);
}

// Round 7
// 9886.433 us; speedup vs baseline: 6.0465x; 6.0465x over previous
//
#include <hip/hip_runtime.h>
#include <stdint.h>

#define TT 128
#define BB 64
#define DD 1024
#define G3 3072

typedef unsigned short u16;
typedef unsigned int u32;
typedef __attribute__((ext_vector_type(8))) short bf16x8;
typedef __attribute__((ext_vector_type(4))) short s16x4;
typedef __attribute__((ext_vector_type(4))) float f32x4;

__device__ __forceinline__ float b2f(u16 h){ u32 u = ((u32)h)<<16; float f; __builtin_memcpy(&f,&u,4); return f; }
__device__ __forceinline__ u16 f2b(float f){ u32 u; __builtin_memcpy(&u,&f,4); u = (u + 0x7fffu + ((u>>16)&1u))>>16; return (u16)u; }
__device__ __forceinline__ float sigm(float x){ return 1.f/(1.f+__expf(-x)); }
__device__ __forceinline__ float tanh_(float x){
  if (x > 10.f) return 1.f;
  if (x < -10.f) return -1.f;
  float e = __expf(2.f*x); return (e-1.f)/(e+1.f);
}

struct DPar {
  const u16 *A1,*A2,*A3,*A4,*A5,*A6;   // bf16 weights
  const float* feat;                    // fp32 features (converted in-flight)
  u16 *ghist,*cb,*qselb,*qnewb,*eb;
  float *scores,*parties,*gf,*ef;
  float *GIGa,*GIGb,*GHG,*GHP,*GIE,*GIPa,*GIPb,*GHE;
  const float *bihg,*bhhg,*bihp,*bhhp,*bihe,*bhhe,*watt;
  const int* spk;
  float* out;
};

// ---- A-fragment loaders (bf16 direct; fp32 converted in-flight) ----
__device__ __forceinline__ void loadA(bf16x8& d, const u16* p){ d = *(const bf16x8*)p; }
__device__ __forceinline__ void loadA(bf16x8& d, const float* p){
  f32x4 lo = *(const f32x4*)p;
  f32x4 hi = *(const f32x4*)(p + 4);
  #pragma unroll
  for (int i = 0; i < 4; ++i) { d[i] = (short)f2b(lo[i]); d[i+4] = (short)f2b(hi[i]); }
}

// ---- fragment-direct 64x64-tile GEMM, K=1024, 4 waves (2 K-halves x 2 N-halves) ----
// C tile cols n0..n0+63 = A[64][1024] * W[n0..n0+63][k0..k0+1023]^T. k0 on W only.
// All plain loads/stores: cross-dispatch coherence handled at kernel boundaries.
template<typename TA>
__device__ __attribute__((noinline)) void gemm_frag(
    const TA* __restrict__ A, const u16* __restrict__ W, int ldW,
    int k0, int n0, float* __restrict__ C, float* red) {
  const int tid = threadIdx.x;
  const int wv  = tid >> 6;
  const int kh  = wv >> 1;
  const int nh  = wv & 1;
  const int lane = tid & 63;
  const int l15 = lane & 15;
  const int l4  = lane >> 4;
  const TA*  Ab = A + (size_t)l15 * DD + kh * 512 + l4 * 8;
  const u16* Wb = W + (size_t)(n0 + nh*32 + l15) * ldW + k0 + kh * 512 + l4 * 8;

  f32x4 acc[4][2];
  #pragma unroll
  for (int i = 0; i < 4; ++i) { acc[i][0] = (f32x4){0,0,0,0}; acc[i][1] = (f32x4){0,0,0,0}; }

  bf16x8 af[2][4], wf[2][2];
  #pragma unroll
  for (int bt = 0; bt < 4; ++bt) loadA(af[0][bt], Ab + (size_t)bt*16*DD);
  wf[0][0] = *(const bf16x8*)(Wb);
  wf[0][1] = *(const bf16x8*)(Wb + (size_t)16*ldW);

  #pragma unroll
  for (int kt = 0; kt < 16; ++kt) {
    const int cur = kt & 1, nxt = cur ^ 1;
    if (kt < 15) {
      const int ko = (kt + 1) * 32;
      #pragma unroll
      for (int bt = 0; bt < 4; ++bt) loadA(af[nxt][bt], Ab + (size_t)bt*16*DD + ko);
      wf[nxt][0] = *(const bf16x8*)(Wb + ko);
      wf[nxt][1] = *(const bf16x8*)(Wb + (size_t)16*ldW + ko);
    }
    #pragma unroll
    for (int bt = 0; bt < 4; ++bt) {
      acc[bt][0] = __builtin_amdgcn_mfma_f32_16x16x32_bf16(af[cur][bt], wf[cur][0], acc[bt][0], 0,0,0);
      acc[bt][1] = __builtin_amdgcn_mfma_f32_16x16x32_bf16(af[cur][bt], wf[cur][1], acc[bt][1], 0,0,0);
    }
  }
  // K-half reduction: kh=1 waves park partials in LDS (16KB), kh=0 add + store.
  if (kh == 1) {
    #pragma unroll
    for (int bt = 0; bt < 4; ++bt)
      #pragma unroll
      for (int nt = 0; nt < 2; ++nt)
        #pragma unroll
        for (int q = 0; q < 4; ++q)
          red[(bt*16 + l4*4 + q)*64 + nh*32 + nt*16 + l15] = acc[bt][nt][q];
  }
  __syncthreads();
  if (kh == 0) {
    #pragma unroll
    for (int bt = 0; bt < 4; ++bt)
      #pragma unroll
      for (int nt = 0; nt < 2; ++nt)
        #pragma unroll
        for (int q = 0; q < 4; ++q) {
          const int row = bt*16 + l4*4 + q;
          const int col = nh*32 + nt*16 + l15;
          C[(size_t)row*G3 + n0 + col] = acc[bt][nt][q] + red[row*64 + col];
        }
  }
}

// ---- combine global GRU (16 blocks x 256 thr): g_t, ghist row t, score_t ----
__device__ void combineG(const DPar& p, int t, int rel) {
  const int gt = rel*256 + (int)threadIdx.x;
  const int b  = gt >> 6;
  const int j0 = (gt & 63) << 4;
  const size_t ob = (size_t)b * G3;
  float gn[16];
  float sc = 0.f;
  #pragma unroll
  for (int gq = 0; gq < 4; ++gq) {
    const int j = j0 + gq*4;
    f32x4 ar = *(const f32x4*)(p.GIGa + ob + j);
    f32x4 az = *(const f32x4*)(p.GIGa + ob + 1024 + j);
    f32x4 an = *(const f32x4*)(p.GIGa + ob + 2048 + j);
    f32x4 br = {0,0,0,0}, bz = {0,0,0,0}, bn = {0,0,0,0};
    f32x4 hr = {0,0,0,0}, hz = {0,0,0,0}, hn = {0,0,0,0};
    if (t) {
      br = *(const f32x4*)(p.GIGb + ob + j);
      bz = *(const f32x4*)(p.GIGb + ob + 1024 + j);
      bn = *(const f32x4*)(p.GIGb + ob + 2048 + j);
      hr = *(const f32x4*)(p.GHG + ob + j);
      hz = *(const f32x4*)(p.GHG + ob + 1024 + j);
      hn = *(const f32x4*)(p.GHG + ob + 2048 + j);
    }
    #pragma unroll
    for (int q = 0; q < 4; ++q) {
      const int jj = j + q;
      float r_ = sigm(ar[q] + br[q] + p.bihg[jj]      + hr[q] + p.bhhg[jj]);
      float z_ = sigm(az[q] + bz[q] + p.bihg[1024+jj] + hz[q] + p.bhhg[1024+jj]);
      float n_ = tanh_(an[q] + bn[q] + p.bihg[2048+jj] + r_*(hn[q] + p.bhhg[2048+jj]));
      float gp = p.gf[(size_t)b*DD + jj];
      float gv = (1.f - z_)*n_ + z_*gp;
      p.gf[(size_t)b*DD + jj] = gv;
      gn[gq*4+q] = gv;
      sc += gv * p.watt[jj];
    }
  }
  bf16x8 h0, h1;
  #pragma unroll
  for (int q = 0; q < 8; ++q) { h0[q] = (short)f2b(gn[q]); h1[q] = (short)f2b(gn[8+q]); }
  u16* gr = p.ghist + (size_t)t*BB*DD + (size_t)b*DD + j0;
  *(bf16x8*)gr = h0; *(bf16x8*)(gr + 8) = h1;
  #pragma unroll
  for (int o = 1; o < 64; o <<= 1) sc += __shfl_xor(sc, o);
  if ((threadIdx.x & 63) == 0) p.scores[t*BB + b] = sc;
}

// ---- combine emotion GRU (16 blocks): e_td, out row td ----
__device__ void combineE(const DPar& p, int td, int rel) {
  const int gt = rel*256 + (int)threadIdx.x;
  const int b  = gt >> 6;
  const int j0 = (gt & 63) << 4;
  const size_t ob = (size_t)b * G3;
  float en[16];
  #pragma unroll
  for (int gq = 0; gq < 4; ++gq) {
    const int j = j0 + gq*4;
    f32x4 ir4 = *(const f32x4*)(p.GIE + ob + j);
    f32x4 iz4 = *(const f32x4*)(p.GIE + ob + 1024 + j);
    f32x4 in4 = *(const f32x4*)(p.GIE + ob + 2048 + j);
    f32x4 hr = {0,0,0,0}, hz = {0,0,0,0}, hn = {0,0,0,0};
    if (td > 0) {
      hr = *(const f32x4*)(p.GHE + ob + j);
      hz = *(const f32x4*)(p.GHE + ob + 1024 + j);
      hn = *(const f32x4*)(p.GHE + ob + 2048 + j);
    }
    #pragma unroll
    for (int q = 0; q < 4; ++q) {
      const int jj = j + q;
      float r_ = sigm(ir4[q] + p.bihe[jj]      + hr[q] + p.bhhe[jj]);
      float z_ = sigm(iz4[q] + p.bihe[1024+jj] + hz[q] + p.bhhe[1024+jj]);
      float n_ = tanh_(in4[q] + p.bihe[2048+jj] + r_*(hn[q] + p.bhhe[2048+jj]));
      float ep = p.ef[(size_t)b*DD + jj];
      float ev = (1.f - z_)*n_ + z_*ep;
      p.ef[(size_t)b*DD + jj] = ev;
      en[gq*4+q] = ev;
    }
  }
  float* orow = p.out + (size_t)td*BB*DD + (size_t)b*DD + j0;
  #pragma unroll
  for (int gq = 0; gq < 4; ++gq) {
    f32x4 v = { en[gq*4], en[gq*4+1], en[gq*4+2], en[gq*4+3] };
    *(f32x4*)(orow + gq*4) = v;
  }
  bf16x8 e0, e1;
  #pragma unroll
  for (int q = 0; q < 8; ++q) { e0[q] = (short)f2b(en[q]); e1[q] = (short)f2b(en[8+q]); }
  u16* er = p.eb + (size_t)b*DD + j0;
  *(bf16x8*)er = e0; *(bf16x8*)(er + 8) = e1;
}

// ---- combine party GRU (16 blocks): speaker slot update; emit qnew_t, qsel_{t+1} ----
__device__ void combineQ(const DPar& p, int t, int rel) {
  const int gt = rel*256 + (int)threadIdx.x;
  const int b  = gt >> 6;
  const int j0 = (gt & 63) << 4;
  const size_t ob = (size_t)b * G3;
  const int spkc = p.spk[t*BB + b];
  const int spkn = (t+1 < TT) ? p.spk[(t+1)*BB + b] : spkc;
  float* prow = p.parties + (size_t)(b*2 + spkc)*DD;
  const float* orow = p.parties + (size_t)(b*2 + spkn)*DD;
  float qn16[16];
  #pragma unroll
  for (int gq = 0; gq < 4; ++gq) {
    const int j = j0 + gq*4;
    f32x4 ar = *(const f32x4*)(p.GIPa + ob + j);
    f32x4 az = *(const f32x4*)(p.GIPa + ob + 1024 + j);
    f32x4 an = *(const f32x4*)(p.GIPa + ob + 2048 + j);
    f32x4 br = {0,0,0,0}, bz = {0,0,0,0}, bn = {0,0,0,0};
    f32x4 hr = {0,0,0,0}, hz = {0,0,0,0}, hn = {0,0,0,0};
    if (t) {
      br = *(const f32x4*)(p.GIPb + ob + j);
      bz = *(const f32x4*)(p.GIPb + ob + 1024 + j);
      bn = *(const f32x4*)(p.GIPb + ob + 2048 + j);
      hr = *(const f32x4*)(p.GHP + ob + j);
      hz = *(const f32x4*)(p.GHP + ob + 1024 + j);
      hn = *(const f32x4*)(p.GHP + ob + 2048 + j);
    }
    #pragma unroll
    for (int q = 0; q < 4; ++q) {
      const int jj = j + q;
      float r_ = sigm(ar[q] + br[q] + p.bihp[jj]      + hr[q] + p.bhhp[jj]);
      float z_ = sigm(az[q] + bz[q] + p.bihp[1024+jj] + hz[q] + p.bhhp[1024+jj]);
      float n_ = tanh_(an[q] + bn[q] + p.bihp[2048+jj] + r_*(hn[q] + p.bhhp[2048+jj]));
      float h  = prow[jj];
      float qv = (1.f - z_)*n_ + z_*h;
      prow[jj] = qv;
      qn16[gq*4+q] = qv;
    }
  }
  bf16x8 qn0, qn1, qs0, qs1;
  #pragma unroll
  for (int q = 0; q < 8; ++q) {
    qn0[q] = (short)f2b(qn16[q]);
    qn1[q] = (short)f2b(qn16[8+q]);
    qs0[q] = (spkn == spkc) ? qn0[q] : (short)f2b(orow[j0+q]);
    qs1[q] = (spkn == spkc) ? qn1[q] : (short)f2b(orow[j0+8+q]);
  }
  u16* qnp = p.qnewb + (size_t)b*DD + j0;
  u16* qsp = p.qselb + (size_t)b*DD + j0;
  *(bf16x8*)qnp = qn0; *(bf16x8*)(qnp+8) = qn1;
  *(bf16x8*)qsp = qs0; *(bf16x8*)(qsp+8) = qs1;
}

// ---- attention (64 blocks, one per batch): c_t = softmax(scores[<t]) . ghist[<t] ----
__device__ void attn_run(const DPar& p, int t, int b, float* smem) {
  float* al = smem;          // [128] alpha
  float* rs = smem + 128;    // [4] wave partials
  float* part = smem + 160;  // [4][64][16]
  const int tid = threadIdx.x;
  float s = (tid < t) ? p.scores[tid*BB + b] : -1e30f;
  if (tid < 128) {
    float m = s;
    #pragma unroll
    for (int o = 1; o < 64; o <<= 1) m = fmaxf(m, __shfl_xor(m, o));
    if ((tid & 63) == 0) rs[tid >> 6] = m;
  }
  __syncthreads();
  const float m = fmaxf(rs[0], rs[1]);
  float e = (tid < t) ? __expf(s - m) : 0.f;
  if (tid < 128) {
    float sum = e;
    #pragma unroll
    for (int o = 1; o < 64; o <<= 1) sum += __shfl_xor(sum, o);
    if ((tid & 63) == 0) rs[2 + (tid >> 6)] = sum;
  }
  __syncthreads();
  if (tid < 128) al[tid] = e / (rs[2] + rs[3]);
  __syncthreads();
  const int ug = tid >> 6, dg = tid & 63;
  float acc[16];
  #pragma unroll
  for (int i = 0; i < 16; ++i) acc[i] = 0.f;
  const u16* gb = p.ghist + (size_t)b*DD + dg*16;
  // 8-row register chunks: 16 loads in flight per wave, one latency per 32 u-steps
  for (int u0 = ug; u0 < t; u0 += 32) {
    bf16x8 g0[8], g1[8]; float av[8];
    #pragma unroll
    for (int i = 0; i < 8; ++i) {
      const int u = u0 + i*4;
      if (u < t) {
        g0[i] = *(const bf16x8*)(gb + (size_t)u*BB*DD);
        g1[i] = *(const bf16x8*)(gb + (size_t)u*BB*DD + 8);
        av[i] = al[u];
      } else {
        av[i] = 0.f;
        g0[i] = (bf16x8){0,0,0,0,0,0,0,0};
        g1[i] = (bf16x8){0,0,0,0,0,0,0,0};
      }
    }
    #pragma unroll
    for (int i = 0; i < 8; ++i)
      #pragma unroll
      for (int d = 0; d < 8; ++d) {
        acc[d]   += av[i] * b2f((u16)g0[i][d]);
        acc[8+d] += av[i] * b2f((u16)g1[i][d]);
      }
  }
  #pragma unroll
  for (int i = 0; i < 4; ++i)
    *(f32x4*)(part + ((size_t)ug*64 + dg)*16 + i*4) = (f32x4){acc[i*4],acc[i*4+1],acc[i*4+2],acc[i*4+3]};
  __syncthreads();
  const int d = tid * 4;
  const int dgf = d >> 4, di = d & 15;
  f32x4 sum = {0,0,0,0};
  #pragma unroll
  for (int u2 = 0; u2 < 4; ++u2) sum += *(f32x4*)(part + ((size_t)u2*64 + dgf)*16 + di);
  s16x4 o;
  #pragma unroll
  for (int q = 0; q < 4; ++q) o[q] = (short)f2b(sum[q]);
  *(s16x4*)(p.cb + (size_t)b*DD + d) = o;
}

// ---- K1: 336 GEMM tile jobs + 64 attention blocks ----
__global__ void __launch_bounds__(256) k1_step(DPar p, int t) {
  __shared__ float smem[4352];
  const int blk = blockIdx.x;
  if (blk < 336) {
    const int g  = blk / 48;
    const int n0 = (blk % 48) * 64;
    switch (g) {
      case 0:            gemm_frag(p.feat + (size_t)t*BB*DD, p.A1, 2048, 0,    n0, p.GIGa, smem); break;
      case 1: if (t)     gemm_frag(p.qselb, p.A1, 2048, 1024, n0, p.GIGb, smem); break;
      case 2: if (t)     gemm_frag(p.ghist + (size_t)(t-1)*BB*DD, p.A2, 1024, 0, n0, p.GHG, smem); break;
      case 3:            gemm_frag(p.feat + (size_t)t*BB*DD, p.A3, 2048, 0,    n0, p.GIPa, smem); break;
      case 4: if (t)     gemm_frag(p.qselb, p.A4, 1024, 0,    n0, p.GHP, smem); break;
      case 5: if (t)     gemm_frag(p.qnewb, p.A5, 1024, 0,    n0, p.GIE, smem); break;   // emotion step t-1
      case 6: if (t > 1) gemm_frag(p.eb,    p.A6, 1024, 0,    n0, p.GHE, smem); break;   // hidden e_{t-2}
    }
  } else if (t) {
    attn_run(p, t, blk - 336, smem);
  }
}

// ---- K2: GIPb(c_t) + combineG(t) + combineE(t-1) ----
__global__ void __launch_bounds__(256) k2_step(DPar p, int t) {
  __shared__ float smem[4096];
  const int blk = blockIdx.x;
  if (blk < 48)      { if (t) gemm_frag(p.cb, p.A3, 2048, 1024, blk*64, p.GIPb, smem); }
  else if (blk < 64) combineG(p, t, blk - 48);
  else               { if (t) combineE(p, t - 1, blk - 64); }
}

// ---- K3: combineQ(t) ----
__global__ void __launch_bounds__(256) k3_step(DPar p, int t) {
  combineQ(p, t, blockIdx.x);
}

// ---- epilogue: emotion GRU inputs for step 127, then combineE(127) ----
__global__ void __launch_bounds__(256) k1_epi(DPar p) {
  __shared__ float smem[4096];
  const int blk = blockIdx.x;
  if (blk < 48) gemm_frag(p.qnewb, p.A5, 1024, 0, blk*64,      p.GIE, smem);
  else          gemm_frag(p.eb,    p.A6, 1024, 0, (blk-48)*64, p.GHE, smem);
}
__global__ void __launch_bounds__(256) k2_epi(DPar p) {
  combineE(p, TT-1, blockIdx.x);
}

// ---- weight fp32 -> bf16 cast ----
__global__ void convertK(const float* __restrict__ Wg, const float* __restrict__ Whg,
                         const float* __restrict__ Wp, const float* __restrict__ Whp,
                         const float* __restrict__ We, const float* __restrict__ Whe,
                         u16* A1, u16* A2, u16* A3, u16* A4, u16* A5, u16* A6) {
  const long n1 = (long)G3*2048/4, n2 = (long)G3*1024/4;
  const long tot = 2*n1 + 4*n2;
  long gid = (long)blockIdx.x*256 + threadIdx.x;
  const long stride = (long)gridDim.x*256;
  for (long i = gid; i < tot; i += stride) {
    const float* src; u16* dst; long o = i;
    if (o < n1) { src = Wg;  dst = A1; }
    else { o -= n1;
      if (o < n2) { src = Whg; dst = A2; }
      else { o -= n2;
        if (o < n1) { src = Wp; dst = A3; }
        else { o -= n1;
          if (o < n2) { src = Whp; dst = A4; }
          else { o -= n2;
            if (o < n2) { src = We; dst = A5; }
            else { o -= n2; src = Whe; dst = A6; }
          }
        }
      }
    }
    f32x4 v = *(const f32x4*)(src + o*4);
    s16x4 w;
    w[0] = (short)f2b(v[0]); w[1] = (short)f2b(v[1]);
    w[2] = (short)f2b(v[2]); w[3] = (short)f2b(v[3]);
    *(s16x4*)(dst + o*4) = w;
  }
}

// ---- zero state + speaker idx (runs every launch; replay/poison-safe) ----
__global__ void initK(float* parties, float* gf, float* ef,
                      u16* cb, u16* qselb, u16* qnewb, u16* eb,
                      const float* spkOH, int* spk) {
  const int i = blockIdx.x*256 + threadIdx.x;
  if (i < BB*2*DD) parties[i] = 0.f;
  if (i < BB*DD) { gf[i] = 0.f; ef[i] = 0.f; cb[i] = 0; qselb[i] = 0; qnewb[i] = 0; eb[i] = 0; }
  if (i < TT*BB) spk[i] = (spkOH[(size_t)i*2 + 1] > 0.5f) ? 1 : 0;
}

extern "C" void kernel_launch(void* const* d_in, const int* in_sizes, int n_in,
                              void* d_out, int out_size, void* d_ws, size_t ws_size,
                              hipStream_t stream) {
  const float* feat  = (const float*)d_in[0];
  const float* spkOH = (const float*)d_in[1];
  const float* Wih_g = (const float*)d_in[2];
  const float* Whh_g = (const float*)d_in[3];
  const float* bih_g = (const float*)d_in[4];
  const float* bhh_g = (const float*)d_in[5];
  const float* Wih_p = (const float*)d_in[6];
  const float* Whh_p = (const float*)d_in[7];
  const float* bih_p = (const float*)d_in[8];
  const float* bhh_p = (const float*)d_in[9];
  const float* Wih_e = (const float*)d_in[10];
  const float* Whh_e = (const float*)d_in[11];
  const float* bih_e = (const float*)d_in[12];
  const float* bhh_e = (const float*)d_in[13];
  const float* watt  = (const float*)d_in[14];

  char* w = (char*)d_ws;
  auto alloc = [&](size_t bytes) -> char* {
    char* r = w; w += (bytes + 255) & ~(size_t)255; return r;
  };
  u16* ghist = (u16*)alloc((size_t)TT*BB*DD*2);
  float* scores = (float*)alloc((size_t)TT*BB*4);
  u16* cb    = (u16*)alloc((size_t)BB*DD*2);
  u16* qselb = (u16*)alloc((size_t)BB*DD*2);
  u16* qnewb = (u16*)alloc((size_t)BB*DD*2);
  u16* eb    = (u16*)alloc((size_t)BB*DD*2);
  float* parties = (float*)alloc((size_t)BB*2*DD*4);
  float* gf  = (float*)alloc((size_t)BB*DD*4);
  float* ef  = (float*)alloc((size_t)BB*DD*4);
  float* GIGa = (float*)alloc((size_t)BB*G3*4);
  float* GIGb = (float*)alloc((size_t)BB*G3*4);
  float* GHG  = (float*)alloc((size_t)BB*G3*4);
  float* GHP  = (float*)alloc((size_t)BB*G3*4);
  float* GIE  = (float*)alloc((size_t)BB*G3*4);
  float* GIPa = (float*)alloc((size_t)BB*G3*4);
  float* GIPb = (float*)alloc((size_t)BB*G3*4);
  float* GHE  = (float*)alloc((size_t)BB*G3*4);
  int* spk    = (int*)alloc((size_t)TT*BB*4);
  u16* A1 = (u16*)alloc((size_t)G3*2048*2);
  u16* A2 = (u16*)alloc((size_t)G3*1024*2);
  u16* A3 = (u16*)alloc((size_t)G3*2048*2);
  u16* A4 = (u16*)alloc((size_t)G3*1024*2);
  u16* A5 = (u16*)alloc((size_t)G3*1024*2);
  u16* A6 = (u16*)alloc((size_t)G3*1024*2);
  const size_t need = (size_t)(w - (char*)d_ws);   // ~75 MB, fits (rounds 2/5)
  if (ws_size < need) return;   // fail validation visibly rather than fault

  hipLaunchKernelGGL(convertK, dim3(2048), dim3(256), 0, stream,
                     Wih_g, Whh_g, Wih_p, Whh_p, Wih_e, Whh_e,
                     A1, A2, A3, A4, A5, A6);
  hipLaunchKernelGGL(initK, dim3(512), dim3(256), 0, stream,
                     parties, gf, ef, cb, qselb, qnewb, eb, spkOH, spk);

  DPar p;
  p.A1 = A1; p.A2 = A2; p.A3 = A3; p.A4 = A4; p.A5 = A5; p.A6 = A6;
  p.feat = feat;
  p.ghist = ghist; p.cb = cb; p.qselb = qselb; p.qnewb = qnewb; p.eb = eb;
  p.scores = scores; p.parties = parties; p.gf = gf; p.ef = ef;
  p.GIGa = GIGa; p.GIGb = GIGb; p.GHG = GHG; p.GHP = GHP; p.GIE = GIE;
  p.GIPa = GIPa; p.GIPb = GIPb; p.GHE = GHE;
  p.bihg = bih_g; p.bhhg = bhh_g; p.bihp = bih_p; p.bhhp = bhh_p;
  p.bihe = bih_e; p.bhhe = bhh_e; p.watt = watt;
  p.spk = spk; p.out = (float*)d_out;

  for (int t = 0; t < TT; ++t) {
    hipLaunchKernelGGL(k1_step, dim3(400), dim3(256), 0, stream, p, t);
    hipLaunchKernelGGL(k2_step, dim3(80),  dim3(256), 0, stream, p, t);
    hipLaunchKernelGGL(k3_step, dim3(16),  dim3(256), 0, stream, p, t);
  }
  hipLaunchKernelGGL(k1_epi, dim3(96), dim3(256), 0, stream, p);
  hipLaunchKernelGGL(k2_epi, dim3(16), dim3(256), 0, stream, p);
}